// Round 12
// baseline (2840.336 us; speedup 1.0000x reference)
//
#include <hip/hip_runtime.h>

// Problem dims (fixed by setup_inputs): T=256, B=64, I=512, H=2048
#define T_DIM 256
#define B_DIM 64
#define I_DIM 512
#define H_DIM 2048
#define BH (B_DIM * H_DIM)      // 131072 floats per timestep slice
#define NBLK 256                // persistent grid: 1 block per CU

typedef __attribute__((ext_vector_type(8))) short bf16x8;
typedef __attribute__((ext_vector_type(4))) float f32x4;

// ---------------------------------------------------------------------
// Agent-scope ops (validated R4-R11): relaxed sc-bit global ops serviced
// at the device coherence point (MALL) — coherent, uncached, no fences.
// Used for: flags, out-writes, and reads that must NOT allocate L2 lines
// (xin + initial h) so consumers' touch-once normal reads stay fresh.
// ---------------------------------------------------------------------
__device__ __forceinline__ unsigned aloadU32(const unsigned* p) {
  return __hip_atomic_load(p, __ATOMIC_RELAXED, __HIP_MEMORY_SCOPE_AGENT);
}
__device__ __forceinline__ float aloadF(const float* p) {
  union { unsigned u; float f; } c;
  c.u = __hip_atomic_load((const unsigned*)p, __ATOMIC_RELAXED,
                          __HIP_MEMORY_SCOPE_AGENT);
  return c.f;
}
__device__ __forceinline__ void astore4(float* p, float a) {
  union { unsigned u; float f; } c; c.f = a;
  __hip_atomic_store((unsigned*)p, c.u, __ATOMIC_RELAXED,
                     __HIP_MEMORY_SCOPE_AGENT);
}

// f32 pair -> packed 2xbf16 (RNE) in one instruction
__device__ __forceinline__ unsigned cvtpk(float lo, float hi) {
  unsigned r;
  asm("v_cvt_pk_bf16_f32 %0, %1, %2" : "=v"(r) : "v"(lo), "v"(hi));
  return r;
}

// bf16 split helpers (W staging only, once)
__device__ __forceinline__ unsigned bf16_rne(float x) {
  union { float f; unsigned u; } c; c.f = x;
  return (c.u + 0x7FFFu + ((c.u >> 16) & 1u)) >> 16;
}
__device__ __forceinline__ float bf16_to_f(unsigned b) {
  union { float f; unsigned u; } c; c.u = b << 16; return c.f;
}
__device__ __forceinline__ void cvt_pair(float x0, float x1,
                                         unsigned& hi, unsigned& lo) {
  unsigned h0 = bf16_rne(x0), h1 = bf16_rne(x1);
  float r0 = x0 - bf16_to_f(h0), r1 = x1 - bf16_to_f(h1);
  unsigned l0 = bf16_rne(r0), l1 = bf16_rne(r1);
  hi = h0 | (h1 << 16);
  lo = l0 | (l1 << 16);
}
__device__ __forceinline__ void cvt8(const float* s, uint4& hi, uint4& lo) {
  float4 a = *(const float4*)s;
  float4 b = *(const float4*)(s + 4);
  cvt_pair(a.x, a.y, hi.x, lo.x);
  cvt_pair(a.z, a.w, hi.y, lo.y);
  cvt_pair(b.x, b.y, hi.z, lo.z);
  cvt_pair(b.z, b.w, hi.w, lo.w);
}

// =====================================================================
// Kernel A: xin = x @ W_ih^T + b_ih + b_hh  (rows m<64 fold t=0:
// out[0] = 0.01*relu(xin[0])).  Unchanged (fp32 VALU).
// =====================================================================
__global__ __launch_bounds__(256) void xin_gemm(
    const float* __restrict__ x, const float* __restrict__ Wih,
    const float* __restrict__ bih, const float* __restrict__ bhh,
    float* __restrict__ out)
{
  __shared__ __align__(16) float As[16][132];
  __shared__ __align__(16) float Bs[16][132];
  const int tid = threadIdx.x;
  const int nb = blockIdx.x & 15, mb = blockIdx.x >> 4;
  const int m0 = mb * 128, n0 = nb * 128;
  const int tx = tid & 15, ty = tid >> 4;

  float acc[8][8];
  #pragma unroll
  for (int i = 0; i < 8; ++i)
    #pragma unroll
    for (int j = 0; j < 8; ++j) acc[i][j] = 0.f;

  for (int k0 = 0; k0 < I_DIM; k0 += 16) {
    __syncthreads();
    {
      const int r = tid >> 1;
      #pragma unroll
      for (int c = 0; c < 2; ++c) {
        const int kq = (tid & 1) * 4 + c * 8;
        float4 va = *(const float4*)&x[(size_t)(m0 + r) * I_DIM + k0 + kq];
        As[kq + 0][r] = va.x; As[kq + 1][r] = va.y;
        As[kq + 2][r] = va.z; As[kq + 3][r] = va.w;
        float4 vb = *(const float4*)&Wih[(size_t)(n0 + r) * I_DIM + k0 + kq];
        Bs[kq + 0][r] = vb.x; Bs[kq + 1][r] = vb.y;
        Bs[kq + 2][r] = vb.z; Bs[kq + 3][r] = vb.w;
      }
    }
    __syncthreads();
    #pragma unroll 4
    for (int k = 0; k < 16; ++k) {
      float a[8], b[8];
      *(float4*)&a[0] = *(const float4*)&As[k][ty * 8];
      *(float4*)&a[4] = *(const float4*)&As[k][ty * 8 + 4];
      *(float4*)&b[0] = *(const float4*)&Bs[k][tx * 4];
      *(float4*)&b[4] = *(const float4*)&Bs[k][64 + tx * 4];
      #pragma unroll
      for (int i = 0; i < 8; ++i)
        #pragma unroll
        for (int j = 0; j < 8; ++j) acc[i][j] += a[i] * b[j];
    }
  }

  float bb[8];
  #pragma unroll
  for (int j = 0; j < 4; ++j) {
    bb[j]     = bih[n0 + tx * 4 + j]      + bhh[n0 + tx * 4 + j];
    bb[4 + j] = bih[n0 + 64 + tx * 4 + j] + bhh[n0 + 64 + tx * 4 + j];
  }
  #pragma unroll
  for (int i = 0; i < 8; ++i) {
    const int m = m0 + ty * 8 + i;
    float v[8];
    #pragma unroll
    for (int j = 0; j < 8; ++j) v[j] = acc[i][j] + bb[j];
    if (m < B_DIM) {
      #pragma unroll
      for (int j = 0; j < 8; ++j) v[j] = 0.01f * fmaxf(v[j], 0.f);
    }
    *(float4*)&out[(size_t)m * H_DIM + n0 + tx * 4] =
        make_float4(v[0], v[1], v[2], v[3]);
    *(float4*)&out[(size_t)m * H_DIM + n0 + 64 + tx * 4] =
        make_float4(v[4], v[5], v[6], v[7]);
  }
}

// =====================================================================
// Kernel B (R12): barrier-free scan, NO pub buffer.
// Consumers read h straight from out[t-1] with NORMAL loads (fp32) and
// cvt_pk to bf16 frags in-register.  Coherence: out[t-1] lines are
// normal-touched ONLY by step-t consumers (xin + initial h use AGENT
// loads so no pre-update line is ever cached); first touch misses to
// MALL (fresh post-astore data), then L2-shared by the XCD's 32 blocks.
// Traffic: 32 MB/step (R11 agent A-frags) -> ~4 MB/step (L2 dedup).
// Flags: producer astores out[t], vmcnt-drains in ALL waves, syncthreads,
// flag = t+1.  Consumer wave polls its 32 producers (same bh, nb' in
// [wid*32,+32)).  No fences anywhere.
// =====================================================================
__global__ __launch_bounds__(256) void ctrnn_scan(
    const float* __restrict__ Whh, float* out, unsigned* slots)
{
  __shared__ __align__(16) uint4 Whi[4096];   // 64 KB
  __shared__ __align__(16) uint4 Wlo[4096];   // 64 KB
  __shared__ __align__(16) f32x4 Red[512];    // 8 KB

  const int tid = threadIdx.x, bid = blockIdx.x;
  const int nb = bid & 127, bh = bid >> 7;
  const int n0 = nb * 16, b0 = bh * 32;

  const int lane = tid & 63, wid = tid >> 6;
  const int fq = lane >> 4, fr = lane & 15;

  // ---- stage W slice ONCE: rows n0..n0+16, all k, frag-packed hi/lo ----
  for (int s = tid; s < 4096; s += 256) {
    const int kcg = s >> 6, l = s & 63;
    const int n = n0 + (l & 15), k = kcg * 32 + (l >> 4) * 8;
    uint4 hi, lo;
    cvt8(&Whh[(size_t)n * H_DIM + k], hi, lo);
    Whi[s] = hi; Wlo[s] = lo;
  }

  // ---- ownership mapping (MFMA C layout: col=lane&15=n, row=b) ----
  const int bt = tid >> 7, jh = (tid >> 6) & 1, ln = tid & 63;
  const int rfr = ln & 15, rfq = ln >> 4;
  const int bl0 = bt * 16 + rfq * 4 + jh * 2;            // local b of 1st
  const size_t oa0 = (size_t)(b0 + bl0) * H_DIM + n0 + rfr;
  const size_t oa1 = oa0 + H_DIM;

  // fp32 h state in registers; AGENT read (no L2 line allocated —
  // consumers will normal-read these out[0] lines at t=1)
  float h0 = aloadF(&out[oa0]);
  float h1 = aloadF(&out[oa1]);

  __syncthreads();   // W staging complete
  // out[0] ready by stream ordering -> flag = 1 immediately
  if (tid == 0)
    __hip_atomic_store(slots + (size_t)bid * 16, 1u, __ATOMIC_RELAXED,
                       __HIP_MEMORY_SCOPE_AGENT);

  // my wave's 32 producer flags: blocks (bh, wid*32 + 0..31)
  const unsigned* myflag =
      slots + (size_t)(bh * 128 + wid * 32 + (lane & 31)) * 16;

  const int baseB = wid * 1024;                      // +kc*64+lane

  for (int t = 1; t < T_DIM; ++t) {
    // xin prefetch: AGENT load (no L2 pollution of out[t] lines, which
    // step-(t+1) consumers will normal-read)
    const float xin0 = aloadF(&out[(size_t)t * BH + oa0]);
    const float xin1 = aloadF(&out[(size_t)t * BH + oa1]);
    asm volatile("" :: "v"(xin0), "v"(xin1));  // keep loads here

    // ---- per-wave flag poll: my 32 producers finished out[t-1] ----
    for (int it = 0; it < (1 << 17); ++it) {
      if (__all(aloadU32(myflag) >= (unsigned)t)) break;
      __builtin_amdgcn_s_sleep(1);
    }

    // ---- GEMM: normal-load h rows (L2-dedup'd), cvt_pk, MFMA ----
    const float* hb = out + (size_t)(t - 1) * BH + wid * 512 + fq * 8;
    const float* hrow0 = hb + (size_t)(b0 + fr) * H_DIM;        // b-tile 0
    const float* hrow1 = hb + (size_t)(b0 + 16 + fr) * H_DIM;   // b-tile 1

    f32x4 acc0 = {0.f, 0.f, 0.f, 0.f}, acc1 = {0.f, 0.f, 0.f, 0.f};
    #pragma unroll
    for (int kc = 0; kc < 16; ++kc) {
      const float4 x0 = *(const float4*)(hrow0 + kc * 32);
      const float4 x1 = *(const float4*)(hrow0 + kc * 32 + 4);
      const float4 y0 = *(const float4*)(hrow1 + kc * 32);
      const float4 y1 = *(const float4*)(hrow1 + kc * 32 + 4);
      union { unsigned w[4]; bf16x8 v; } a0, a1;
      a0.w[0] = cvtpk(x0.x, x0.y); a0.w[1] = cvtpk(x0.z, x0.w);
      a0.w[2] = cvtpk(x1.x, x1.y); a0.w[3] = cvtpk(x1.z, x1.w);
      a1.w[0] = cvtpk(y0.x, y0.y); a1.w[1] = cvtpk(y0.z, y0.w);
      a1.w[2] = cvtpk(y1.x, y1.y); a1.w[3] = cvtpk(y1.z, y1.w);
      const uint4 bh4 = Whi[baseB + kc * 64 + lane];
      const uint4 bl4 = Wlo[baseB + kc * 64 + lane];
      acc0 = __builtin_amdgcn_mfma_f32_16x16x32_bf16(
          a0.v, *(const bf16x8*)&bh4, acc0, 0, 0, 0);
      acc0 = __builtin_amdgcn_mfma_f32_16x16x32_bf16(
          a0.v, *(const bf16x8*)&bl4, acc0, 0, 0, 0);
      acc1 = __builtin_amdgcn_mfma_f32_16x16x32_bf16(
          a1.v, *(const bf16x8*)&bh4, acc1, 0, 0, 0);
      acc1 = __builtin_amdgcn_mfma_f32_16x16x32_bf16(
          a1.v, *(const bf16x8*)&bl4, acc1, 0, 0, 0);
    }

    // ---- cross-wave K reduce ----
    Red[(wid * 2 + 0) * 64 + lane] = acc0;
    Red[(wid * 2 + 1) * 64 + lane] = acc1;
    __syncthreads();

    float s0 = 0.f, s1 = 0.f;
    #pragma unroll
    for (int w = 0; w < 4; ++w) {
      const float2 p = *(const float2*)(
          (const char*)&Red[(w * 2 + bt) * 64 + ln] + jh * 8);
      s0 += p.x; s1 += p.y;
    }

    // ---- leaky-relu update (fp32 register state) ----
    h0 = 0.99f * h0 + 0.01f * fmaxf(xin0 + s0, 0.f);
    h1 = 0.99f * h1 + 0.01f * fmaxf(xin1 + s1, 0.f);

    // ---- write h[t] (agent write-through), drain ALL waves, flag ----
    astore4(&out[(size_t)t * BH + oa0], h0);
    astore4(&out[(size_t)t * BH + oa1], h1);
    if (t == T_DIM - 1) {
      astore4(&out[(size_t)T_DIM * BH + oa0], h0);  // h_last
      astore4(&out[(size_t)T_DIM * BH + oa1], h1);
    } else {
      asm volatile("s_waitcnt vmcnt(0)" ::: "memory");  // per-wave drain
      __syncthreads();                                  // all waves drained
      if (tid == 0)
        __hip_atomic_store(slots + (size_t)bid * 16, (unsigned)(t + 1),
                           __ATOMIC_RELAXED, __HIP_MEMORY_SCOPE_AGENT);
    }
  }
}

// =====================================================================
extern "C" void kernel_launch(void* const* d_in, const int* in_sizes, int n_in,
                              void* d_out, int out_size, void* d_ws, size_t ws_size,
                              hipStream_t stream) {
  const float* x    = (const float*)d_in[0];
  const float* Wih  = (const float*)d_in[1];
  const float* bih  = (const float*)d_in[2];
  const float* Whh  = (const float*)d_in[3];
  const float* bhh  = (const float*)d_in[4];
  float* out = (float*)d_out;

  unsigned* slots = (unsigned*)d_ws;   // 16 KB of flags

  hipMemsetAsync(d_ws, 0, 32768, stream);  // reset flags every call

  xin_gemm<<<dim3(2048), dim3(256), 0, stream>>>(x, Wih, bih, bhh, out);
  ctrnn_scan<<<dim3(NBLK), dim3(256), 0, stream>>>(Whh, out, slots);
}